// Round 1
// baseline (196.899 us; speedup 1.0000x reference)
//
#include <hip/hip_runtime.h>
#include <math.h>

typedef short s16x8 __attribute__((ext_vector_type(8)));
typedef float f32x4 __attribute__((ext_vector_type(4)));

#define N_NODES 100000
#define N_EDGESC 1000000
#define NODE_DIM 64
#define HID 128

// round-to-nearest-even f32 -> bf16 bits
__device__ __forceinline__ unsigned short f2bf(float f){
  unsigned u = __float_as_uint(f);
  u += 0x7fffu + ((u >> 16) & 1u);
  return (unsigned short)(u >> 16);
}

__global__ void cast_node_kernel(const float* __restrict__ src,
                                 unsigned short* __restrict__ dst, int n4){
  int i = blockIdx.x * blockDim.x + threadIdx.x;
  int stride = gridDim.x * blockDim.x;
  for (; i < n4; i += stride){
    const float4 v = reinterpret_cast<const float4*>(src)[i];
    ushort4 o;
    o.x = f2bf(v.x); o.y = f2bf(v.y); o.z = f2bf(v.z); o.w = f2bf(v.w);
    reinterpret_cast<ushort4*>(dst)[i] = o;
  }
}

// build W1^T, W2^T in bf16: wt[n*128 + k] = W[k*128 + n]
__global__ void prep_w_kernel(const float* __restrict__ w1, const float* __restrict__ w2,
                              unsigned short* __restrict__ w1t, unsigned short* __restrict__ w2t){
  int i = blockIdx.x * blockDim.x + threadIdx.x;
  if (i < 16384){
    int k = i >> 7, n = i & 127;
    w1t[n*128 + k] = f2bf(w1[i]);
  } else if (i < 32768){
    int j = i - 16384;
    int k = j >> 7, n = j & 127;
    w2t[n*128 + k] = f2bf(w2[j]);
  }
}

// Fused 3-layer edge MLP.
// Per wave: 32 edges (2 e-tiles of 16).  mfma_f32_16x16x32_bf16 with
//   A = W^T fragment (row = out-channel n = nt*16 + (lane&15), k = t*32 + (lane>>4)*8 + j)
//   B = feat/h fragment (col = edge = lane&15, same k)
//   D: lane holds h[edge = lane&15][n = nt*16 + (lane>>4)*4 + r]  (m89-verified layout)
// W staged in 32KB LDS (XOR swizzle (row&7)<<4 to break the 256B-stride conflict),
// re-staged for layer 2.  h1 crosses D-layout -> B-layout via a wave-private 4KB LDS slot.
__global__ __launch_bounds__(256, 3) void mlp_main(
    const int* __restrict__ eidx,              // [2][E] (int32 per harness convention)
    const unsigned short* __restrict__ nodeb,  // [N][64] bf16 bits
    const unsigned short* __restrict__ w1tg,   // [128][128] bf16, transposed
    const unsigned short* __restrict__ w2tg,
    const float* __restrict__ b1, const float* __restrict__ b2,
    const float* __restrict__ w3, const float* __restrict__ b3,
    float* __restrict__ out)
{
  __shared__ unsigned short wlds[128*128];   // 32 KB, swizzled
  __shared__ unsigned short h1lds[4*16*128]; // 16 KB, 4KB per wave, swizzled

  const int tid  = threadIdx.x;
  const int wave = tid >> 6;
  const int lane = tid & 63;
  const int q    = lane >> 4;   // quadrant
  const int s    = lane & 15;
  const char* wbase = (const char*)wlds;
  char* hbase = (char*)h1lds + wave * 4096;

  const long ebase = (long)blockIdx.x * 128 + wave * 32;

  // ---- gather feat B-fragments straight from global (bf16 node table, L2/L3-hot)
  s16x8 bf1[2][4];
  #pragma unroll
  for (int et = 0; et < 2; ++et){
    long e = ebase + et*16 + s;
    if (e > (long)N_EDGESC - 1) e = N_EDGESC - 1;
    const int is = eidx[e];
    const int id = eidx[N_EDGESC + e];
    #pragma unroll
    for (int t = 0; t < 4; ++t){
      const int node = (t < 2) ? is : id;
      const int c = (t & 1) * 32 + q * 8;    // k = t*32 + q*8 maps to src cols (t<2) / dst cols
      bf1[et][t] = *reinterpret_cast<const s16x8*>(nodeb + node * NODE_DIM + c);
    }
  }

  // ---- stage W1^T into LDS (swizzled)
  #pragma unroll
  for (int j = 0; j < 8; ++j){
    const int c = j * 256 + tid;                         // 16B chunk id, 2048 total
    const int4 v = reinterpret_cast<const int4*>(w1tg)[c];
    const unsigned addr = (unsigned)(c * 16) ^ ((((unsigned)c >> 4) & 7u) << 4);
    *reinterpret_cast<int4*>((char*)wlds + addr) = v;
  }
  __syncthreads();

  f32x4 acc[2][8];
  #pragma unroll
  for (int et = 0; et < 2; ++et)
    #pragma unroll
    for (int nt = 0; nt < 8; ++nt)
      acc[et][nt] = (f32x4){0.f, 0.f, 0.f, 0.f};

  // ---- layer 1
  #pragma unroll
  for (int t = 0; t < 4; ++t){
    #pragma unroll
    for (int nt = 0; nt < 8; ++nt){
      const int n = nt * 16 + s;
      const unsigned addr = (unsigned)(n * 256 + t * 64 + q * 16) ^ (((unsigned)(n & 7)) << 4);
      const s16x8 a = *reinterpret_cast<const s16x8*>(wbase + addr);
      acc[0][nt] = __builtin_amdgcn_mfma_f32_16x16x32_bf16(a, bf1[0][t], acc[0][nt], 0, 0, 0);
      acc[1][nt] = __builtin_amdgcn_mfma_f32_16x16x32_bf16(a, bf1[1][t], acc[1][nt], 0, 0, 0);
    }
  }

  // ---- bias + relu + bf16, D-layout -> B-layout via wave-private LDS slot
  s16x8 bf2[2][4];
  #pragma unroll
  for (int et = 0; et < 2; ++et){
    #pragma unroll
    for (int nt = 0; nt < 8; ++nt){
      const float4 bb = *reinterpret_cast<const float4*>(b1 + nt*16 + q*4);
      ushort4 pk;
      pk.x = f2bf(fmaxf(acc[et][nt][0] + bb.x, 0.f));
      pk.y = f2bf(fmaxf(acc[et][nt][1] + bb.y, 0.f));
      pk.z = f2bf(fmaxf(acc[et][nt][2] + bb.z, 0.f));
      pk.w = f2bf(fmaxf(acc[et][nt][3] + bb.w, 0.f));
      // row = edge s, cols n = nt*16 + q*4 .. +3  (8B store)
      const unsigned addr = (unsigned)(s * 256 + nt * 32 + q * 8) ^ (((unsigned)(s & 7)) << 4);
      *reinterpret_cast<ushort4*>(hbase + addr) = pk;
    }
    #pragma unroll
    for (int t = 0; t < 4; ++t){
      const unsigned addr = (unsigned)(s * 256 + t * 64 + q * 16) ^ (((unsigned)(s & 7)) << 4);
      bf2[et][t] = *reinterpret_cast<const s16x8*>(hbase + addr);
    }
  }

  __syncthreads();
  // ---- stage W2^T (reuse the same 32KB)
  #pragma unroll
  for (int j = 0; j < 8; ++j){
    const int c = j * 256 + tid;
    const int4 v = reinterpret_cast<const int4*>(w2tg)[c];
    const unsigned addr = (unsigned)(c * 16) ^ ((((unsigned)c >> 4) & 7u) << 4);
    *reinterpret_cast<int4*>((char*)wlds + addr) = v;
  }
  __syncthreads();

  #pragma unroll
  for (int et = 0; et < 2; ++et)
    #pragma unroll
    for (int nt = 0; nt < 8; ++nt)
      acc[et][nt] = (f32x4){0.f, 0.f, 0.f, 0.f};

  // ---- layer 2
  #pragma unroll
  for (int t = 0; t < 4; ++t){
    #pragma unroll
    for (int nt = 0; nt < 8; ++nt){
      const int n = nt * 16 + s;
      const unsigned addr = (unsigned)(n * 256 + t * 64 + q * 16) ^ (((unsigned)(n & 7)) << 4);
      const s16x8 a = *reinterpret_cast<const s16x8*>(wbase + addr);
      acc[0][nt] = __builtin_amdgcn_mfma_f32_16x16x32_bf16(a, bf2[0][t], acc[0][nt], 0, 0, 0);
      acc[1][nt] = __builtin_amdgcn_mfma_f32_16x16x32_bf16(a, bf2[1][t], acc[1][nt], 0, 0, 0);
    }
  }

  // ---- layer 3: bias+relu, dot with W3, quadrant reduce, sigmoid
  const float bias3 = b3[0];
  #pragma unroll
  for (int et = 0; et < 2; ++et){
    float p = 0.f;
    #pragma unroll
    for (int nt = 0; nt < 8; ++nt){
      const float4 bb = *reinterpret_cast<const float4*>(b2 + nt*16 + q*4);
      const float4 ww = *reinterpret_cast<const float4*>(w3 + nt*16 + q*4);
      p += fmaxf(acc[et][nt][0] + bb.x, 0.f) * ww.x;
      p += fmaxf(acc[et][nt][1] + bb.y, 0.f) * ww.y;
      p += fmaxf(acc[et][nt][2] + bb.z, 0.f) * ww.z;
      p += fmaxf(acc[et][nt][3] + bb.w, 0.f) * ww.w;
    }
    p += __shfl_xor(p, 16);
    p += __shfl_xor(p, 32);
    const long e = ebase + et*16 + s;
    if (lane < 16 && e < N_EDGESC){
      out[e] = 1.f / (1.f + expf(-(p + bias3)));
    }
  }
}

extern "C" void kernel_launch(void* const* d_in, const int* in_sizes, int n_in,
                              void* d_out, int out_size, void* d_ws, size_t ws_size,
                              hipStream_t stream){
  const float* node_rep = (const float*)d_in[0];
  const int*   eidx     = (const int*)d_in[1];   // harness: integer -> const int*
  const float* W1 = (const float*)d_in[2];
  const float* b1 = (const float*)d_in[3];
  const float* W2 = (const float*)d_in[4];
  const float* b2 = (const float*)d_in[5];
  const float* W3 = (const float*)d_in[6];
  const float* b3 = (const float*)d_in[7];
  float* out = (float*)d_out;

  unsigned short* nodeb = (unsigned short*)d_ws;
  unsigned short* w1t = (unsigned short*)((char*)d_ws + (size_t)N_NODES * NODE_DIM * 2);
  unsigned short* w2t = w1t + 128 * 128;

  cast_node_kernel<<<2048, 256, 0, stream>>>(node_rep, nodeb, N_NODES * NODE_DIM / 4);
  prep_w_kernel<<<128, 256, 0, stream>>>(W1, W2, w1t, w2t);

  const int nblocks = (N_EDGESC + 127) / 128;
  mlp_main<<<nblocks, 256, 0, stream>>>(eidx, nodeb, w1t, w2t, b1, b2, W3, b3, out);
}